// Round 4
// baseline (238.780 us; speedup 1.0000x reference)
//
#include <hip/hip_runtime.h>
#include <stdint.h>

#define NCH    30                  // channels per cell (cell = 120 B)
#define TPW    64                  // one wave per block
#define TILE   64                  // cells per tile (one per lane)
#define TWORDS (TILE * NCH)        // 1920 floats per array per tile
#define TF4    (2 * TWORDS / 4)    // 960 float4 chunks per tile (pred+lab)
#define LOADS  (TF4 / TPW)         // 15 float4 loads per lane per tile
#define NBLK   1280                // 5 blocks/CU * 256 CUs (LDS-limited fit)

__device__ __forceinline__ float iou_f(float x1, float y1, float w1, float h1,
                                       float x2, float y2, float w2, float h2) {
    float l1 = x1 - 0.5f * w1, r1 = x1 + 0.5f * w1;
    float t1 = y1 - 0.5f * h1, b1 = y1 + 0.5f * h1;
    float l2 = x2 - 0.5f * w2, r2 = x2 + 0.5f * w2;
    float t2 = y2 - 0.5f * h2, b2 = y2 + 0.5f * h2;
    float in_h = fminf(b1, b2) - fmaxf(t1, t2);
    float in_w = fminf(r1, r2) - fmaxf(l1, l2);
    float inter = (in_h < 0.f || in_w < 0.f) ? 0.f : in_h * in_w;
    float a1 = (b1 - t1) * (r1 - l1);
    float a2 = (b2 - t2) * (r2 - l2);
    return inter / (a1 + a2 - inter);
}

// Compute the 5 loss terms for the cell held in LDS at pp/lp, accumulate.
__device__ __forceinline__ void cell_loss(const float* __restrict__ pp,
                                          const float* __restrict__ lp,
                                          float& v0, float& v1, float& v2,
                                          float& v3, float& v4) {
    const float2 l01 = *(const float2*)(lp);        // mask, gx
    const float mask = l01.x;
    if (mask == 0.f) return;

    const float2 l23 = *(const float2*)(lp + 2);    // gy, gw
    const float2 l45 = *(const float2*)(lp + 4);    // gh, -
    const float gx = l01.y, gy = l23.x, gw = l23.y, gh = l45.x;

    const float2 p01 = *(const float2*)(pp);        // -, b1x
    const float2 p23 = *(const float2*)(pp + 2);    // b1y, b1w
    const float2 p45 = *(const float2*)(pp + 4);    // b1h, -
    const float2 p67 = *(const float2*)(pp + 6);    // b2x, b2y
    const float2 p89 = *(const float2*)(pp + 8);    // b2w, b2h

    const float i1 = iou_f(p01.y, p23.x, p23.y, p45.x, gx, gy, gw, gh);
    const float i2 = iou_f(p67.x, p67.y, p89.x, p89.y, gx, gy, gw, gh);
    const bool best = (i1 >= i2);
    const float sx = best ? p01.y : p67.x;
    const float sy = best ? p23.x : p67.y;
    const float sw = best ? p23.y : p89.x;
    const float sh = best ? p45.x : p89.y;
    const float imax = best ? i1 : i2;
    const float imin = best ? i2 : i1;

    const float center = 5.f * ((sx - gx) * (sx - gx) + (sy - gy) * (sy - gy));
    const float dw = sqrtf(sw) - sqrtf(gw);
    const float dh = sqrtf(sh) - sqrtf(gh);
    const float wh = 5.f * (dw * dw + dh * dh);

    float cls = 0.f;
#pragma unroll
    for (int k = 0; k < 10; ++k) {                  // channels 10..29
        const float2 pd = *(const float2*)(pp + 10 + 2 * k);
        const float2 ld = *(const float2*)(lp + 10 + 2 * k);
        const float dx = pd.x - ld.x;
        const float dy = pd.y - ld.y;
        cls += dx * dx + dy * dy;
    }

    v0 += center * mask;
    v1 += wh * mask;
    v2 += imax * mask;
    v3 += imin * mask;
    v4 += cls * mask;
}

// Persistent single-wave blocks. Reg-staged double-buffered LDS:
//   global_load_dwordx4 -> VGPR (deeply pipelined, per-register vmcnt)
//   -> ds_write_b128 -> LDS -> strided per-cell compute.
// No global_load_lds (its per-wave LDS-DMA completions appear to serialize at
// full memory latency: R2/R3 both measured ~1175 cy/load). No barriers at all.
__global__ __launch_bounds__(TPW) void yolo_partial(const float* __restrict__ pred,
                                                    const float* __restrict__ lab,
                                                    float* __restrict__ partial,
                                                    int n_cells) {
    __shared__ float s[4 * TWORDS];                 // 2 buffers x 3840 floats = 30720 B
    const int lane = threadIdx.x;
    const int bid = blockIdx.x;
    const int NB = gridDim.x;
    const int nt = n_cells / TILE;                  // 12544 full tiles

    float v0 = 0.f, v1 = 0.f, v2 = 0.f, v3 = 0.f, v4 = 0.f;

    float4 r[LOADS];                                // staging registers (60 VGPR)

    // Issue 15 coalesced float4 loads of tile `tile` into r[].
    auto LOAD = [&](int tile) {
#pragma unroll
        for (int i = 0; i < LOADS; ++i) {
            const int idx = i * TPW + lane;         // float4 index in [0, 960)
            const float* src = (idx < TWORDS / 4)
                ? (pred + (size_t)tile * TWORDS + (size_t)idx * 4)
                : (lab  + (size_t)tile * TWORDS + (size_t)(idx - TWORDS / 4) * 4);
            r[i] = *(const float4*)src;
        }
    };
    // Spill r[] into LDS buffer (linear layout; compiler inserts the precise
    // per-register vmcnt waits right before each ds_write).
    auto WRITE = [&](float* buf) {
#pragma unroll
        for (int i = 0; i < LOADS; ++i) {
            const int idx = i * TPW + lane;
            *(float4*)(buf + (size_t)idx * 4) = r[i];
        }
    };

    float* A = s;                                   // buffer being computed from
    float* B = s + 2 * TWORDS;                      // buffer being filled

    if (bid < nt) {
        LOAD(bid);
        WRITE(A);                                   // waits (progressively) on loads
        if (bid + NB < nt) LOAD(bid + NB);          // tile t+1 in flight over compute

        for (int t = bid; t < nt; t += NB) {
            cell_loss(A + lane * NCH, A + TWORDS + lane * NCH, v0, v1, v2, v3, v4);

            if (t + NB < nt) {
                WRITE(B);                           // residual vmcnt wait lands here
                if (t + 2 * NB < nt) LOAD(t + 2 * NB);
            }
            float* tmp = A; A = B; B = tmp;
        }
    }

    // Remainder cells (n_cells % 64) — direct from global. Never taken for
    // 802816 cells; kept for shape safety.
    const int rem_start = nt * TILE;
    if (bid == 0 && rem_start < n_cells) {
        for (int c = rem_start + lane; c < n_cells; c += TPW) {
            cell_loss(pred + (size_t)c * NCH, lab + (size_t)c * NCH,
                      v0, v1, v2, v3, v4);
        }
    }

    // ---- wave (64-lane) shuffle reduction, one wave per block ----
#pragma unroll
    for (int off = 32; off > 0; off >>= 1) {
        v0 += __shfl_down(v0, off);
        v1 += __shfl_down(v1, off);
        v2 += __shfl_down(v2, off);
        v3 += __shfl_down(v3, off);
        v4 += __shfl_down(v4, off);
    }
    if (lane == 0) {
        float* p = partial + (size_t)bid * 5;
        p[0] = v0; p[1] = v1; p[2] = v2; p[3] = v3; p[4] = v4;
    }
}

// Reduce n_blocks x 5 partials -> out[0..4]. One block.
__global__ __launch_bounds__(256) void final_reduce(const float* __restrict__ partial,
                                                    float* __restrict__ out,
                                                    int n_blocks) {
    __shared__ float red[5][4];
    const int tid = threadIdx.x;
    float v0 = 0.f, v1 = 0.f, v2 = 0.f, v3 = 0.f, v4 = 0.f;
    for (int b = tid; b < n_blocks; b += 256) {
        const float* p = partial + (size_t)b * 5;
        v0 += p[0]; v1 += p[1]; v2 += p[2]; v3 += p[3]; v4 += p[4];
    }
#pragma unroll
    for (int off = 32; off > 0; off >>= 1) {
        v0 += __shfl_down(v0, off);
        v1 += __shfl_down(v1, off);
        v2 += __shfl_down(v2, off);
        v3 += __shfl_down(v3, off);
        v4 += __shfl_down(v4, off);
    }
    const int wave = tid >> 6;
    const int lane = tid & 63;
    if (lane == 0) {
        red[0][wave] = v0;
        red[1][wave] = v1;
        red[2][wave] = v2;
        red[3][wave] = v3;
        red[4][wave] = v4;
    }
    __syncthreads();
    if (tid < 5) {
        float sacc = 0.f;
#pragma unroll
        for (int w = 0; w < 4; ++w) sacc += red[tid][w];
        out[tid] = sacc;
    }
}

extern "C" void kernel_launch(void* const* d_in, const int* in_sizes, int n_in,
                              void* d_out, int out_size, void* d_ws, size_t ws_size,
                              hipStream_t stream) {
    const float* pred = (const float*)d_in[0];
    const float* lab  = (const float*)d_in[1];
    float* out = (float*)d_out;
    float* partial = (float*)d_ws;                 // 1280*5*4 = 25,600 B

    const int n_cells = in_sizes[0] / NCH;         // 802816

    hipLaunchKernelGGL(yolo_partial, dim3(NBLK), dim3(TPW), 0, stream,
                       pred, lab, partial, n_cells);
    hipLaunchKernelGGL(final_reduce, dim3(1), dim3(256), 0, stream,
                       partial, out, NBLK);
}

// Round 5
// 209.568 us; speedup vs baseline: 1.1394x; 1.1394x over previous
//
#include <hip/hip_runtime.h>
#include <stdint.h>

#define NCH    30                  // channels per cell (cell = 120 B)
#define TPW    64                  // one wave per block
#define TILE   64                  // cells per tile (one per lane)
#define TWORDS (TILE * NCH)        // 1920 floats per array per tile
#define NF4    (2 * TWORDS / 4)    // 960 float4 chunks per tile (pred+lab)
#define LOADS  (NF4 / TPW)         // 15 float4 loads per lane per tile
#define C0     8                   // staging chunk sizes (8 + 7 = 15)
#define C1     7
#define NBLK   2560                // 10 single-wave blocks per CU * 256 CUs

__device__ __forceinline__ float iou_f(float x1, float y1, float w1, float h1,
                                       float x2, float y2, float w2, float h2) {
    float l1 = x1 - 0.5f * w1, r1 = x1 + 0.5f * w1;
    float t1 = y1 - 0.5f * h1, b1 = y1 + 0.5f * h1;
    float l2 = x2 - 0.5f * w2, r2 = x2 + 0.5f * w2;
    float t2 = y2 - 0.5f * h2, b2 = y2 + 0.5f * h2;
    float in_h = fminf(b1, b2) - fmaxf(t1, t2);
    float in_w = fminf(r1, r2) - fmaxf(l1, l2);
    float inter = (in_h < 0.f || in_w < 0.f) ? 0.f : in_h * in_w;
    float a1 = (b1 - t1) * (r1 - l1);
    float a2 = (b2 - t2) * (r2 - l2);
    return inter / (a1 + a2 - inter);
}

// Compute the 5 loss terms for the cell held at pp/lp (LDS or global), accumulate.
__device__ __forceinline__ void cell_loss(const float* __restrict__ pp,
                                          const float* __restrict__ lp,
                                          float& v0, float& v1, float& v2,
                                          float& v3, float& v4) {
    const float2 l01 = *(const float2*)(lp);        // mask, gx
    const float mask = l01.x;
    if (mask == 0.f) return;

    const float2 l23 = *(const float2*)(lp + 2);    // gy, gw
    const float2 l45 = *(const float2*)(lp + 4);    // gh, -
    const float gx = l01.y, gy = l23.x, gw = l23.y, gh = l45.x;

    const float2 p01 = *(const float2*)(pp);        // -, b1x
    const float2 p23 = *(const float2*)(pp + 2);    // b1y, b1w
    const float2 p45 = *(const float2*)(pp + 4);    // b1h, -
    const float2 p67 = *(const float2*)(pp + 6);    // b2x, b2y
    const float2 p89 = *(const float2*)(pp + 8);    // b2w, b2h

    const float i1 = iou_f(p01.y, p23.x, p23.y, p45.x, gx, gy, gw, gh);
    const float i2 = iou_f(p67.x, p67.y, p89.x, p89.y, gx, gy, gw, gh);
    const bool best = (i1 >= i2);
    const float sx = best ? p01.y : p67.x;
    const float sy = best ? p23.x : p67.y;
    const float sw = best ? p23.y : p89.x;
    const float sh = best ? p45.x : p89.y;
    const float imax = best ? i1 : i2;
    const float imin = best ? i2 : i1;

    const float center = 5.f * ((sx - gx) * (sx - gx) + (sy - gy) * (sy - gy));
    const float dw = sqrtf(sw) - sqrtf(gw);
    const float dh = sqrtf(sh) - sqrtf(gh);
    const float wh = 5.f * (dw * dw + dh * dh);

    float cls = 0.f;
#pragma unroll
    for (int k = 0; k < 10; ++k) {                  // channels 10..29
        const float2 pd = *(const float2*)(pp + 10 + 2 * k);
        const float2 ld = *(const float2*)(lp + 10 + 2 * k);
        const float dx = pd.x - ld.x;
        const float dy = pd.y - ld.y;
        cls += dx * dx + dy * dy;
    }

    v0 += center * mask;
    v1 += wh * mask;
    v2 += imax * mask;
    v3 += imin * mask;
    v4 += cls * mask;
}

// Persistent single-wave blocks, 10 per CU (15,360 B LDS each, no dbuf).
// Per tile: reg-stage in two short chunks (global_load_dwordx4 -> VGPR ->
// ds_write_b128; live range never crosses compute => no spill), then compute.
// No barriers (single wave, in-order LDS ops). Latency hidden by TLP.
__global__ __launch_bounds__(TPW) void yolo_partial(const float* __restrict__ pred,
                                                    const float* __restrict__ lab,
                                                    float* __restrict__ partial,
                                                    int n_cells) {
    __shared__ float s[2 * TWORDS];                 // 3840 floats = 15,360 B
    const int lane = threadIdx.x;
    const int bid = blockIdx.x;
    const int NB = gridDim.x;
    const int nt = n_cells / TILE;                  // 12544 full tiles

    float v0 = 0.f, v1 = 0.f, v2 = 0.f, v3 = 0.f, v4 = 0.f;

    for (int t = bid; t < nt; t += NB) {
        const size_t base = (size_t)t * TWORDS;

        // ---- stage chunk 0: float4 idx = i*64+lane, i in [0,8) ----
        {
            float4 ra[C0];
#pragma unroll
            for (int i = 0; i < C0; ++i) {
                const int idx = i * TPW + lane;     // [0, 512)
                const float* src = (idx < TWORDS / 4)
                    ? (pred + base + (size_t)idx * 4)
                    : (lab  + base + (size_t)(idx - TWORDS / 4) * 4);
                ra[i] = *(const float4*)src;
            }
#pragma unroll
            for (int i = 0; i < C0; ++i) {
                const int idx = i * TPW + lane;
                *(float4*)(s + (size_t)idx * 4) = ra[i];
            }
        }
        // ---- stage chunk 1: i in [8,15) ----
        {
            float4 rb[C1];
#pragma unroll
            for (int i = 0; i < C1; ++i) {
                const int idx = (C0 + i) * TPW + lane;  // [512, 960)
                const float* src = (idx < TWORDS / 4)
                    ? (pred + base + (size_t)idx * 4)
                    : (lab  + base + (size_t)(idx - TWORDS / 4) * 4);
                rb[i] = *(const float4*)src;
            }
#pragma unroll
            for (int i = 0; i < C1; ++i) {
                const int idx = (C0 + i) * TPW + lane;
                *(float4*)(s + (size_t)idx * 4) = rb[i];
            }
        }

        // ---- compute this wave's 64 cells (one per lane) from LDS ----
        cell_loss(s + lane * NCH, s + TWORDS + lane * NCH, v0, v1, v2, v3, v4);
    }

    // Remainder cells (n_cells % 64) — direct from global. Never taken for
    // 802816 cells; kept for shape safety.
    const int rem_start = nt * TILE;
    if (bid == 0 && rem_start < n_cells) {
        for (int c = rem_start + lane; c < n_cells; c += TPW) {
            cell_loss(pred + (size_t)c * NCH, lab + (size_t)c * NCH,
                      v0, v1, v2, v3, v4);
        }
    }

    // ---- wave (64-lane) shuffle reduction, one wave per block ----
#pragma unroll
    for (int off = 32; off > 0; off >>= 1) {
        v0 += __shfl_down(v0, off);
        v1 += __shfl_down(v1, off);
        v2 += __shfl_down(v2, off);
        v3 += __shfl_down(v3, off);
        v4 += __shfl_down(v4, off);
    }
    if (lane == 0) {
        float* p = partial + (size_t)bid * 5;
        p[0] = v0; p[1] = v1; p[2] = v2; p[3] = v3; p[4] = v4;
    }
}

// Reduce n_blocks x 5 partials -> out[0..4]. One block.
__global__ __launch_bounds__(256) void final_reduce(const float* __restrict__ partial,
                                                    float* __restrict__ out,
                                                    int n_blocks) {
    __shared__ float red[5][4];
    const int tid = threadIdx.x;
    float v0 = 0.f, v1 = 0.f, v2 = 0.f, v3 = 0.f, v4 = 0.f;
    for (int b = tid; b < n_blocks; b += 256) {
        const float* p = partial + (size_t)b * 5;
        v0 += p[0]; v1 += p[1]; v2 += p[2]; v3 += p[3]; v4 += p[4];
    }
#pragma unroll
    for (int off = 32; off > 0; off >>= 1) {
        v0 += __shfl_down(v0, off);
        v1 += __shfl_down(v1, off);
        v2 += __shfl_down(v2, off);
        v3 += __shfl_down(v3, off);
        v4 += __shfl_down(v4, off);
    }
    const int wave = tid >> 6;
    const int lane = tid & 63;
    if (lane == 0) {
        red[0][wave] = v0;
        red[1][wave] = v1;
        red[2][wave] = v2;
        red[3][wave] = v3;
        red[4][wave] = v4;
    }
    __syncthreads();
    if (tid < 5) {
        float sacc = 0.f;
#pragma unroll
        for (int w = 0; w < 4; ++w) sacc += red[tid][w];
        out[tid] = sacc;
    }
}

extern "C" void kernel_launch(void* const* d_in, const int* in_sizes, int n_in,
                              void* d_out, int out_size, void* d_ws, size_t ws_size,
                              hipStream_t stream) {
    const float* pred = (const float*)d_in[0];
    const float* lab  = (const float*)d_in[1];
    float* out = (float*)d_out;
    float* partial = (float*)d_ws;                 // 2560*5*4 = 51,200 B

    const int n_cells = in_sizes[0] / NCH;         // 802816

    hipLaunchKernelGGL(yolo_partial, dim3(NBLK), dim3(TPW), 0, stream,
                       pred, lab, partial, n_cells);
    hipLaunchKernelGGL(final_reduce, dim3(1), dim3(256), 0, stream,
                       partial, out, NBLK);
}